// Round 7
// baseline (324.475 us; speedup 1.0000x reference)
//
#include <hip/hip_runtime.h>
#include <hip/hip_bf16.h>
#include <stdint.h>

// GroupTorchGRU: B=1024, U=8, I=H=512, fp32 in/out.
// R7: K1 prepass (fp32->bf16 into d_ws) + K2 BARRIER-FREE fused GEMM+gates:
//  - no LDS, no __syncthreads: each wave independently computes a 16(batch)
//    x 32(h) tile of ALL 6 gate GEMMs (acc = 48 VGPRs), loading A/B MFMA
//    fragments directly from global (L1/L2-cached; weights L2-resident per
//    XCD via x%8 swizzle). Kills the s_barrier+vmcnt(0) convoy that capped
//    R4/R5/R6.
//  - fully unrolled K=16 loop, immediate-offset 16B loads, no per-iter
//    address math; compiler free to pipeline with vmcnt(N).
//  - __launch_bounds__(256,4): VGPR cap 128 (R6 spilled at 96-acc + staging;
//    this design is ~90 persistent -> no spill; WRITE_SIZE is the tripwire).
// Fallback: proven single-kernel path if ws too small.

#define B_ 1024
#define U_ 8
#define I_ 512
#define H_ 512
#define KDIM 512

#define NX (B_ * U_ * I_)
#define NW (U_ * 3 * H_ * I_)
#define OFF_X 0
#define OFF_H NX
#define OFF_WIH (2 * NX)
#define OFF_WHH (2 * NX + NW)
#define NTOT (2 * NX + 2 * NW)
#define WS_NEED ((size_t)NTOT * 2)

typedef __attribute__((ext_vector_type(8))) short short8;
typedef __attribute__((ext_vector_type(4))) float floatx4;

__device__ __forceinline__ unsigned int pk2bf(float a, float b) {
    float2 f2; f2.x = a; f2.y = b;
    union { __hip_bfloat162 h; unsigned int u; } cv;
    cv.h = __float22bfloat162_rn(f2);
    return cv.u;
}

// ---------------- K1: fp32 -> bf16 prepass ----------------
__global__ __launch_bounds__(256)
void convert_bf16_kernel(const float* __restrict__ x, const float* __restrict__ h,
                         const float* __restrict__ wih, const float* __restrict__ whh,
                         unsigned short* __restrict__ ws)
{
    const size_t base = ((size_t)blockIdx.x * 256 + threadIdx.x) * 8;
    const float* src; size_t off;
    if (base < (size_t)OFF_H)        { src = x;   off = OFF_X; }
    else if (base < (size_t)OFF_WIH) { src = h;   off = OFF_H; }
    else if (base < (size_t)OFF_WHH) { src = wih; off = OFF_WIH; }
    else                             { src = whh; off = OFF_WHH; }
    const float4 v0 = *(const float4*)(src + (base - off));
    const float4 v1 = *(const float4*)(src + (base - off) + 4);
    uint4 o;
    o.x = pk2bf(v0.x, v0.y);
    o.y = pk2bf(v0.z, v0.w);
    o.z = pk2bf(v1.x, v1.y);
    o.w = pk2bf(v1.z, v1.w);
    *(uint4*)(ws + base) = o;
}

// ---------------- K2: barrier-free fused bf16 GEMM + GRU gates ----------------
// Wave tile: 16 batch rows x 32 h cols, all 6 gates (gx r/z/n, gh r/z/n).
// A-fragment (16x16x32 bf16): lane holds A[m = lane&15][k = (lane>>4)*8 + j].
// C/D: col = lane&15, row = (lane>>4)*4 + reg.
__global__ __launch_bounds__(256, 4)
void gru_main_kernel(const unsigned short* __restrict__ ws,
                     const float* __restrict__ hidden,
                     const float* __restrict__ b_ih,
                     const float* __restrict__ b_hh,
                     float* __restrict__ out)
{
    // x = u*16 + n32 (x%8 spreads n-tiles across XCDs -> weight set 3MB/XCD)
    const int un  = blockIdx.x;
    const int u   = un >> 4;
    const int n0  = (un & 15) * 32;
    const int lane = threadIdx.x & 63;
    const int wave = threadIdx.x >> 6;
    const int m0  = (blockIdx.y * 4 + wave) * 16;
    const int lr  = lane & 15;
    const int q   = lane >> 4;

    // Per-lane fragment pointers (k advances via immediate offsets).
    const unsigned short* xp = ws + OFF_X + ((size_t)(m0 + lr) * U_ + u) * I_ + q * 8;
    const unsigned short* hp = ws + OFF_H + ((size_t)(m0 + lr) * U_ + u) * H_ + q * 8;

    // Uniform weight slab bases (SGPRs): 0..2 = W_ih r/z/n, 3..5 = W_hh r/z/n
    const unsigned short* wbase[6];
    #pragma unroll
    for (int g = 0; g < 3; ++g) {
        wbase[g]     = ws + OFF_WIH + (size_t)(u * 3 + g) * (H_ * I_);
        wbase[g + 3] = ws + OFF_WHH + (size_t)(u * 3 + g) * (H_ * I_);
    }
    // Lane-varying column offsets shared by all 6 slabs (elements).
    int voff[2];
    #pragma unroll
    for (int nt = 0; nt < 2; ++nt)
        voff[nt] = (n0 + nt * 16 + lr) * I_ + q * 8;

    floatx4 acc[6][2];
    #pragma unroll
    for (int g = 0; g < 6; ++g)
        #pragma unroll
        for (int nt = 0; nt < 2; ++nt)
            acc[g][nt] = (floatx4){0.f, 0.f, 0.f, 0.f};

    #pragma unroll
    for (int it = 0; it < KDIM / 32; ++it) {
        const int k0 = it * 32;
        const short8 ax = *(const short8*)(xp + k0);
        const short8 ah = *(const short8*)(hp + k0);
        #pragma unroll
        for (int g = 0; g < 3; ++g) {
            #pragma unroll
            for (int nt = 0; nt < 2; ++nt) {
                const short8 bx = *(const short8*)(wbase[g] + voff[nt] + k0);
                const short8 bh = *(const short8*)(wbase[g + 3] + voff[nt] + k0);
                acc[g][nt]     = __builtin_amdgcn_mfma_f32_16x16x32_bf16(ax, bx, acc[g][nt], 0, 0, 0);
                acc[g + 3][nt] = __builtin_amdgcn_mfma_f32_16x16x32_bf16(ah, bh, acc[g + 3][nt], 0, 0, 0);
            }
        }
    }

    // ---- epilogue: wave-local, no exchange ----
    const float* bih = b_ih + u * (3 * H_);
    const float* bhh = b_hh + u * (3 * H_);
    #pragma unroll
    for (int nt = 0; nt < 2; ++nt) {
        const int col = n0 + nt * 16 + lr;
        const float bir  = bih[col],          bhr = bhh[col];
        const float biz  = bih[H_ + col],     bhz = bhh[H_ + col];
        const float bin_ = bih[2 * H_ + col], bhn = bhh[2 * H_ + col];
        #pragma unroll
        for (int r = 0; r < 4; ++r) {
            const int row = m0 + q * 4 + r;
            const size_t gidx = ((size_t)row * U_ + u) * H_ + col;
            const float hprev = hidden[gidx];
            const float xr = acc[0][nt][r] + bir;
            const float xz = acc[1][nt][r] + biz;
            const float xn = acc[2][nt][r] + bin_;
            const float hr = acc[3][nt][r] + bhr;
            const float hz = acc[4][nt][r] + bhz;
            const float hn = acc[5][nt][r] + bhn;
            const float rg = 1.f / (1.f + __expf(-(xr + hr)));
            const float zg = 1.f / (1.f + __expf(-(xz + hz)));
            const float ng = tanhf(xn + rg * hn);
            out[gidx] = (1.f - zg) * ng + zg * hprev;
        }
    }
}

// ---------------- Fallback (proven R3 path): used only if ws too small ----------------
#define LSTR 40
#define ESTR 68
union SmemF {
    short bf[8][64 * LSTR];
    float ep[3][64 * ESTR];
};

__global__ __launch_bounds__(512, 4)
void gru_fallback_kernel(const float* __restrict__ inputs, const float* __restrict__ hidden,
                         const float* __restrict__ W_ih, const float* __restrict__ W_hh,
                         const float* __restrict__ b_ih, const float* __restrict__ b_hh,
                         float* __restrict__ out)
{
    const int nb = blockIdx.x;
    const int mb = blockIdx.y;
    const int u  = blockIdx.z;
    const int b0 = mb * 64, h0 = nb * 64;
    const int tid = threadIdx.x, lane = tid & 63, wave = tid >> 6;
    const int lr = lane & 15, q = lane >> 4;
    const int wm = wave & 1, wn = (wave >> 1) & 1, g2 = wave >> 2;

    __shared__ SmemF smem;

    const float* srcs[8]; int rstr[8];
    srcs[0] = inputs + ((size_t)b0 * U_ + u) * I_;         rstr[0] = U_ * I_;
    srcs[1] = hidden + ((size_t)b0 * U_ + u) * H_;         rstr[1] = U_ * H_;
    srcs[2] = W_ih + ((size_t)(u * 3 + 0) * H_ + h0) * I_; rstr[2] = I_;
    srcs[3] = W_ih + ((size_t)(u * 3 + 1) * H_ + h0) * I_; rstr[3] = I_;
    srcs[4] = W_ih + ((size_t)(u * 3 + 2) * H_ + h0) * I_; rstr[4] = I_;
    srcs[5] = W_hh + ((size_t)(u * 3 + 0) * H_ + h0) * H_; rstr[5] = H_;
    srcs[6] = W_hh + ((size_t)(u * 3 + 1) * H_ + h0) * H_; rstr[6] = H_;
    srcs[7] = W_hh + ((size_t)(u * 3 + 2) * H_ + h0) * H_; rstr[7] = H_;

    const int srow = tid >> 3, c4 = (tid & 7) * 4;
    const float* tb[8];
    #pragma unroll
    for (int s = 0; s < 8; ++s) tb[s] = srcs[s] + (size_t)srow * rstr[s] + c4;

    floatx4 acc[3][2][2];
    #pragma unroll
    for (int g = 0; g < 3; ++g)
        #pragma unroll
        for (int mt = 0; mt < 2; ++mt)
            #pragma unroll
            for (int nt = 0; nt < 2; ++nt) acc[g][mt][nt] = (floatx4){0.f, 0.f, 0.f, 0.f};

    const int aslab = g2, bbase = 2 + 3 * g2;
    float4 pre[8];
    #pragma unroll
    for (int s = 0; s < 8; ++s) pre[s] = *(const float4*)(tb[s]);

    for (int k0 = 0; k0 < KDIM; k0 += 32) {
        #pragma unroll
        for (int s = 0; s < 8; ++s) {
            uint2 w; w.x = pk2bf(pre[s].x, pre[s].y); w.y = pk2bf(pre[s].z, pre[s].w);
            *(uint2*)&smem.bf[s][srow * LSTR + c4] = w;
        }
        __syncthreads();
        if (k0 + 32 < KDIM) {
            #pragma unroll
            for (int s = 0; s < 8; ++s) pre[s] = *(const float4*)(tb[s] + k0 + 32);
        }
        short8 afr[2];
        #pragma unroll
        for (int mt = 0; mt < 2; ++mt)
            afr[mt] = *(const short8*)&smem.bf[aslab][(wm * 32 + mt * 16 + lr) * LSTR + q * 8];
        #pragma unroll
        for (int g = 0; g < 3; ++g) {
            const short8 bf0 = *(const short8*)&smem.bf[bbase + g][(wn * 32 + lr) * LSTR + q * 8];
            const short8 bf1 = *(const short8*)&smem.bf[bbase + g][(wn * 32 + 16 + lr) * LSTR + q * 8];
            #pragma unroll
            for (int mt = 0; mt < 2; ++mt) {
                acc[g][mt][0] = __builtin_amdgcn_mfma_f32_16x16x32_bf16(afr[mt], bf0, acc[g][mt][0], 0, 0, 0);
                acc[g][mt][1] = __builtin_amdgcn_mfma_f32_16x16x32_bf16(afr[mt], bf1, acc[g][mt][1], 0, 0, 0);
            }
        }
        __syncthreads();
    }

    const float* bih = b_ih + u * (3 * H_);
    const float* bhh = b_hh + u * (3 * H_);
    if (g2 == 1) {
        #pragma unroll
        for (int nt = 0; nt < 2; ++nt) {
            const int col = wn * 32 + nt * 16 + lr;
            const float bhr = bhh[h0 + col], bhz = bhh[H_ + h0 + col], bhn = bhh[2 * H_ + h0 + col];
            #pragma unroll
            for (int mt = 0; mt < 2; ++mt)
                #pragma unroll
                for (int r = 0; r < 4; ++r) {
                    const int row = wm * 32 + mt * 16 + q * 4 + r;
                    smem.ep[0][row * ESTR + col] = acc[0][mt][nt][r] + bhr;
                    smem.ep[1][row * ESTR + col] = acc[1][mt][nt][r] + bhz;
                    smem.ep[2][row * ESTR + col] = acc[2][mt][nt][r] + bhn;
                }
        }
    }
    __syncthreads();
    if (g2 == 0) {
        #pragma unroll
        for (int nt = 0; nt < 2; ++nt) {
            const int col = wn * 32 + nt * 16 + lr, hcol = h0 + col;
            const float bir = bih[hcol], biz = bih[H_ + hcol], bin_ = bih[2 * H_ + hcol];
            #pragma unroll
            for (int mt = 0; mt < 2; ++mt)
                #pragma unroll
                for (int r = 0; r < 4; ++r) {
                    const int row = wm * 32 + mt * 16 + q * 4 + r;
                    const size_t gidx = ((size_t)(b0 + row) * U_ + u) * H_ + hcol;
                    const float hprev = hidden[gidx];
                    const float hr = smem.ep[0][row * ESTR + col];
                    const float hz = smem.ep[1][row * ESTR + col];
                    const float hn = smem.ep[2][row * ESTR + col];
                    const float xr = acc[0][mt][nt][r] + bir;
                    const float xz = acc[1][mt][nt][r] + biz;
                    const float xn = acc[2][mt][nt][r] + bin_;
                    const float rg = 1.f / (1.f + __expf(-(xr + hr)));
                    const float zg = 1.f / (1.f + __expf(-(xz + hz)));
                    const float ng = tanhf(xn + rg * hn);
                    out[gidx] = (1.f - zg) * ng + zg * hprev;
                }
        }
    }
}

extern "C" void kernel_launch(void* const* d_in, const int* in_sizes, int n_in,
                              void* d_out, int out_size, void* d_ws, size_t ws_size,
                              hipStream_t stream) {
    const float* inputs = (const float*)d_in[0];
    const float* hidden = (const float*)d_in[1];
    const float* W_ih   = (const float*)d_in[2];
    const float* W_hh   = (const float*)d_in[3];
    const float* b_ih   = (const float*)d_in[4];
    const float* b_hh   = (const float*)d_in[5];
    float* out = (float*)d_out;

    if (ws_size >= WS_NEED) {
        unsigned short* ws = (unsigned short*)d_ws;
        convert_bf16_kernel<<<NTOT / 2048, 256, 0, stream>>>(inputs, hidden, W_ih, W_hh, ws);
        // x = u*16 + n32 (128), y = batch chunk (16); 4 waves/block, 1 tile/wave
        dim3 grid(128, 16, 1);
        gru_main_kernel<<<grid, 256, 0, stream>>>(ws, hidden, b_ih, b_hh, out);
    } else {
        dim3 grid(8, 16, 8);
        gru_fallback_kernel<<<grid, 512, 0, stream>>>(inputs, hidden, W_ih, W_hh, b_ih, b_hh, out);
    }
}

// Round 8
// 174.348 us; speedup vs baseline: 1.8611x; 1.8611x over previous
//
#include <hip/hip_runtime.h>
#include <hip/hip_bf16.h>
#include <stdint.h>

// GroupTorchGRU: B=1024, U=8, I=H=512, fp32 in/out.
// R8: K1 prepass (fp32->bf16 into d_ws) + K2 fused GEMM+gates:
//  - BM=128 x BN=64, 512 threads, gate-split (waves 0-3 gx / 4-7 gh),
//    wave tile 64x32 per 3 gates using v_mfma_f32_32x32x16_bf16:
//    12 MFMA per 10 ds_read_b128 per iter (2x R5 FLOP/LDS-byte).
//  - __launch_bounds__(512,2): ~155 VGPR fits under 256 cap -> NO spill
//    (R6's regression was the 128 cap; WRITE_SIZE is the tripwire).
//  - double-buffered global_load_lds (BK=32, 2x40KB), XOR swizzle verified
//    conflict-free for both staging and 32x32 fragment reads.
//  - XCD-aware grid: x%8 = nb -> 3MB weight set per XCD L2.
// Fallback: proven R3 single-kernel path if ws too small.

#define B_ 1024
#define U_ 8
#define I_ 512
#define H_ 512
#define KDIM 512

#define NX (B_ * U_ * I_)
#define NW (U_ * 3 * H_ * I_)
#define OFF_X 0
#define OFF_H NX
#define OFF_WIH (2 * NX)
#define OFF_WHH (2 * NX + NW)
#define NTOT (2 * NX + 2 * NW)
#define WS_NEED ((size_t)NTOT * 2)

#define BM 128
#define BN 64
#define BK 32
#define NITER (KDIM / BK)        // 16
#define BUF_B 40960              // X 8KB + H 8KB + 6 x 4KB weights

typedef __attribute__((ext_vector_type(8))) short short8;
typedef __attribute__((ext_vector_type(4))) float floatx4;
typedef __attribute__((ext_vector_type(16))) float floatx16;

__device__ __forceinline__ unsigned int pk2bf(float a, float b) {
    float2 f2; f2.x = a; f2.y = b;
    union { __hip_bfloat162 h; unsigned int u; } cv;
    cv.h = __float22bfloat162_rn(f2);
    return cv.u;
}

__device__ __forceinline__ void async16(const void* g, void* l) {
    __builtin_amdgcn_global_load_lds(
        (const __attribute__((address_space(1))) void*)g,
        (__attribute__((address_space(3))) void*)l, 16, 0, 0);
}

// ---------------- K1: fp32 -> bf16 prepass ----------------
__global__ __launch_bounds__(256)
void convert_bf16_kernel(const float* __restrict__ x, const float* __restrict__ h,
                         const float* __restrict__ wih, const float* __restrict__ whh,
                         unsigned short* __restrict__ ws)
{
    const size_t base = ((size_t)blockIdx.x * 256 + threadIdx.x) * 8;
    const float* src; size_t off;
    if (base < (size_t)OFF_H)        { src = x;   off = OFF_X; }
    else if (base < (size_t)OFF_WIH) { src = h;   off = OFF_H; }
    else if (base < (size_t)OFF_WHH) { src = wih; off = OFF_WIH; }
    else                             { src = whh; off = OFF_WHH; }
    const float4 v0 = *(const float4*)(src + (base - off));
    const float4 v1 = *(const float4*)(src + (base - off) + 4);
    uint4 o;
    o.x = pk2bf(v0.x, v0.y);
    o.y = pk2bf(v0.z, v0.w);
    o.z = pk2bf(v1.x, v1.y);
    o.w = pk2bf(v1.z, v1.w);
    *(uint4*)(ws + base) = o;
}

// ---------------- K2: fused bf16 GEMM + GRU gates (32x32x16 MFMA) ----------------
// Buffer (40KB): X slab [0,8K) 128r x 32k; H [8K,16K); W slab w at 16K+w*4K,
// 64r x 32k. Rows are 64B (32 bf16); 128B "line" = 2 rows = 8 x 16B slots.
// Physical slot p of line L holds logical slot p ^ (L&7),
// logical slot = (row&1)*4 + kchunk(16B).
__global__ __launch_bounds__(512, 2)
void gru_main_kernel(const unsigned short* __restrict__ ws,
                     const float* __restrict__ hidden,
                     const float* __restrict__ b_ih,
                     const float* __restrict__ b_hh,
                     float* __restrict__ out)
{
    const int u  = blockIdx.x >> 3;   // x%8 = nb -> XCD-local weights
    const int nb = blockIdx.x & 7;
    const int mb = blockIdx.y;        // 0..7
    const int b0 = mb * BM;
    const int h0 = nb * BN;

    const int tid  = threadIdx.x;
    const int lane = tid & 63;
    const int wave = tid >> 6;        // 0..7
    const int l5   = lane & 31;       // fragment row (m or n)
    const int kh8  = lane >> 5;       // which 8-k subchunk within a k-half
    const int p    = wave & 3;        // quadrant within gate-group
    const int wm   = p & 1;           // 64-row half of BM=128
    const int wn   = p >> 1;          // 32-col half of BN=64
    const int g2   = wave >> 2;       // 0: gx, 1: gh

    __shared__ __align__(16) char smem[2 * BUF_B];   // 80KB

    // ---- staging: 40 x 1KB instrs per buffer, 5 per wave ----
    const unsigned short* baseX = ws + OFF_X + ((size_t)b0 * U_ + u) * I_;
    const unsigned short* baseH = ws + OFF_H + ((size_t)b0 * U_ + u) * H_;
    const unsigned short* wb[6];
    #pragma unroll
    for (int w = 0; w < 3; ++w) {
        wb[w]     = ws + OFF_WIH + ((size_t)(u * 3 + w) * H_ + h0) * I_;
        wb[w + 3] = ws + OFF_WHH + ((size_t)(u * 3 + w) * H_ + h0) * H_;
    }

    const unsigned short* gptr[5];
    int ldsoff[5];
    #pragma unroll
    for (int i = 0; i < 5; ++i) {
        const int j = wave * 5 + i;
        const unsigned short* sbase; int rstr, group, soff;
        if (j < 8)       { sbase = baseX; rstr = U_ * I_; group = j;     soff = 0; }
        else if (j < 16) { sbase = baseH; rstr = U_ * H_; group = j - 8; soff = 8192; }
        else             { const int w = (j - 16) >> 2;
                           sbase = wb[w]; rstr = I_; group = (j - 16) & 3;
                           soff = 16384 + w * 4096; }
        const int line = group * 8 + (lane >> 3);
        const int pos  = (lane & 7) ^ (line & 7);   // logical slot staged by this lane
        const int row  = 2 * line + (pos >> 2);
        const int ch   = pos & 3;
        gptr[i]   = sbase + (size_t)row * rstr + ch * 8;
        ldsoff[i] = soff + group * 1024 + lane * 16;
    }

    // ---- fragment read offsets (within-slab bytes) ----
    // A (m-tile mt, k-half kh): r = wm*64 + mt*32 + l5, chunk c = kh*2 + kh8
    int aoff[2][2], boff[2];
    #pragma unroll
    for (int mt = 0; mt < 2; ++mt)
        #pragma unroll
        for (int kh = 0; kh < 2; ++kh) {
            const int r = wm * 64 + mt * 32 + l5;
            const int c = kh * 2 + kh8;
            const int line = r >> 1;
            const int pp = (((r & 1) * 4 + c)) ^ (line & 7);
            aoff[mt][kh] = line * 128 + pp * 16;
        }
    #pragma unroll
    for (int kh = 0; kh < 2; ++kh) {
        const int r = wn * 32 + l5;
        const int c = kh * 2 + kh8;
        const int line = r >> 1;
        const int pp = (((r & 1) * 4 + c)) ^ (line & 7);
        boff[kh] = line * 128 + pp * 16;
    }

    floatx16 acc[3][2];
    #pragma unroll
    for (int g = 0; g < 3; ++g)
        #pragma unroll
        for (int mt = 0; mt < 2; ++mt)
            #pragma unroll
            for (int r = 0; r < 16; ++r) acc[g][mt][r] = 0.f;

    // ---- prologue: loads for buffer 0 ----
    #pragma unroll
    for (int i = 0; i < 5; ++i) {
        async16(gptr[i], smem + ldsoff[i]);
        gptr[i] += BK;
    }

    for (int it = 0; it < NITER; ++it) {
        const int cur = it & 1;
        __syncthreads();   // drains buf[cur] loads (in flight through prev MFMA phase)

        if (it + 1 < NITER) {
            const int nxt = ((it + 1) & 1) * BUF_B;
            #pragma unroll
            for (int i = 0; i < 5; ++i) {
                async16(gptr[i], smem + nxt + ldsoff[i]);
                gptr[i] += BK;
            }
        }

        const char* base  = smem + cur * BUF_B;
        const char* abase = base + g2 * 8192;     // X for gx, H for gh
        short8 a[2][2];
        #pragma unroll
        for (int mt = 0; mt < 2; ++mt)
            #pragma unroll
            for (int kh = 0; kh < 2; ++kh)
                a[mt][kh] = *(const short8*)(abase + aoff[mt][kh]);
        #pragma unroll
        for (int g = 0; g < 3; ++g) {
            const char* bslab = base + 16384 + (g2 * 3 + g) * 4096;
            #pragma unroll
            for (int kh = 0; kh < 2; ++kh) {
                const short8 bf = *(const short8*)(bslab + boff[kh]);
                #pragma unroll
                for (int mt = 0; mt < 2; ++mt)
                    acc[g][mt] = __builtin_amdgcn_mfma_f32_32x32x16_bf16(
                        a[mt][kh], bf, acc[g][mt], 0, 0, 0);
            }
        }
    }

    // ---- epilogue: 2 per-mt rounds; lane-matched gh->gx exchange ----
    // C/D 32x32: col = l5, row = (reg&3) + 8*(reg>>2) + 4*kh8.
    // ep layout: float4[(g*4 + p)*64 + lane][qr], qr=0..3 -> 48KB (fits smem).
    float4* ep = (float4*)smem;
    const float* bih = b_ih + u * (3 * H_);
    const float* bhh = b_hh + u * (3 * H_);
    const int col  = h0 + wn * 32 + l5;
    const float bir  = bih[col],          bhr = bhh[col];
    const float biz  = bih[H_ + col],     bhz = bhh[H_ + col];
    const float bin_ = bih[2 * H_ + col], bhn = bhh[2 * H_ + col];

    #pragma unroll
    for (int mt = 0; mt < 2; ++mt) {
        __syncthreads();   // round 0: all K-loop LDS reads done; round 1: ep reuse
        if (g2 == 1) {
            #pragma unroll
            for (int g = 0; g < 3; ++g)
                #pragma unroll
                for (int qr = 0; qr < 4; ++qr)
                    ep[((g * 4 + p) * 64 + lane) * 4 + qr] =
                        (float4){acc[g][mt][qr * 4 + 0], acc[g][mt][qr * 4 + 1],
                                 acc[g][mt][qr * 4 + 2], acc[g][mt][qr * 4 + 3]};
        }
        __syncthreads();
        if (g2 == 0) {
            #pragma unroll
            for (int qr = 0; qr < 4; ++qr) {
                const float4 hrv = ep[((0 * 4 + p) * 64 + lane) * 4 + qr];
                const float4 hzv = ep[((1 * 4 + p) * 64 + lane) * 4 + qr];
                const float4 hnv = ep[((2 * 4 + p) * 64 + lane) * 4 + qr];
                #pragma unroll
                for (int rr = 0; rr < 4; ++rr) {
                    const int reg = qr * 4 + rr;
                    const int row = wm * 64 + mt * 32 + (reg & 3) + 8 * (reg >> 2) + 4 * kh8;
                    const size_t gidx = ((size_t)(b0 + row) * U_ + u) * H_ + col;
                    const float hprev = hidden[gidx];
                    const float hr = (rr == 0 ? hrv.x : rr == 1 ? hrv.y : rr == 2 ? hrv.z : hrv.w) + bhr;
                    const float hz = (rr == 0 ? hzv.x : rr == 1 ? hzv.y : rr == 2 ? hzv.z : hzv.w) + bhz;
                    const float hn = (rr == 0 ? hnv.x : rr == 1 ? hnv.y : rr == 2 ? hnv.z : hnv.w) + bhn;
                    const float xr = acc[0][mt][reg] + bir;
                    const float xz = acc[1][mt][reg] + biz;
                    const float xn = acc[2][mt][reg] + bin_;
                    const float rg = 1.f / (1.f + __expf(-(xr + hr)));
                    const float zg = 1.f / (1.f + __expf(-(xz + hz)));
                    const float ng = tanhf(xn + rg * hn);
                    out[gidx] = (1.f - zg) * ng + zg * hprev;
                }
            }
        }
    }
}

// ---------------- Fallback (proven R3 path): used only if ws too small ----------------
#define LSTR 40
#define ESTR 68
union SmemF {
    short bf[8][64 * LSTR];
    float ep[3][64 * ESTR];
};

__global__ __launch_bounds__(512, 4)
void gru_fallback_kernel(const float* __restrict__ inputs, const float* __restrict__ hidden,
                         const float* __restrict__ W_ih, const float* __restrict__ W_hh,
                         const float* __restrict__ b_ih, const float* __restrict__ b_hh,
                         float* __restrict__ out)
{
    const int nb = blockIdx.x;
    const int mb = blockIdx.y;
    const int u  = blockIdx.z;
    const int b0 = mb * 64, h0 = nb * 64;
    const int tid = threadIdx.x, lane = tid & 63, wave = tid >> 6;
    const int lr = lane & 15, q = lane >> 4;
    const int wm = wave & 1, wn = (wave >> 1) & 1, g2 = wave >> 2;

    __shared__ SmemF smem;

    const float* srcs[8]; int rstr[8];
    srcs[0] = inputs + ((size_t)b0 * U_ + u) * I_;         rstr[0] = U_ * I_;
    srcs[1] = hidden + ((size_t)b0 * U_ + u) * H_;         rstr[1] = U_ * H_;
    srcs[2] = W_ih + ((size_t)(u * 3 + 0) * H_ + h0) * I_; rstr[2] = I_;
    srcs[3] = W_ih + ((size_t)(u * 3 + 1) * H_ + h0) * I_; rstr[3] = I_;
    srcs[4] = W_ih + ((size_t)(u * 3 + 2) * H_ + h0) * I_; rstr[4] = I_;
    srcs[5] = W_hh + ((size_t)(u * 3 + 0) * H_ + h0) * H_; rstr[5] = H_;
    srcs[6] = W_hh + ((size_t)(u * 3 + 1) * H_ + h0) * H_; rstr[6] = H_;
    srcs[7] = W_hh + ((size_t)(u * 3 + 2) * H_ + h0) * H_; rstr[7] = H_;

    const int srow = tid >> 3, c4 = (tid & 7) * 4;
    const float* tb[8];
    #pragma unroll
    for (int s = 0; s < 8; ++s) tb[s] = srcs[s] + (size_t)srow * rstr[s] + c4;

    floatx4 acc[3][2][2];
    #pragma unroll
    for (int g = 0; g < 3; ++g)
        #pragma unroll
        for (int mt = 0; mt < 2; ++mt)
            #pragma unroll
            for (int nt = 0; nt < 2; ++nt) acc[g][mt][nt] = (floatx4){0.f, 0.f, 0.f, 0.f};

    const int aslab = g2, bbase = 2 + 3 * g2;
    float4 pre[8];
    #pragma unroll
    for (int s = 0; s < 8; ++s) pre[s] = *(const float4*)(tb[s]);

    for (int k0 = 0; k0 < KDIM; k0 += 32) {
        #pragma unroll
        for (int s = 0; s < 8; ++s) {
            uint2 w; w.x = pk2bf(pre[s].x, pre[s].y); w.y = pk2bf(pre[s].z, pre[s].w);
            *(uint2*)&smem.bf[s][srow * LSTR + c4] = w;
        }
        __syncthreads();
        if (k0 + 32 < KDIM) {
            #pragma unroll
            for (int s = 0; s < 8; ++s) pre[s] = *(const float4*)(tb[s] + k0 + 32);
        }
        short8 afr[2];
        #pragma unroll
        for (int mt = 0; mt < 2; ++mt)
            afr[mt] = *(const short8*)&smem.bf[aslab][(wm * 32 + mt * 16 + lr) * LSTR + q * 8];
        #pragma unroll
        for (int g = 0; g < 3; ++g) {
            const short8 bf0 = *(const short8*)&smem.bf[bbase + g][(wn * 32 + lr) * LSTR + q * 8];
            const short8 bf1 = *(const short8*)&smem.bf[bbase + g][(wn * 32 + 16 + lr) * LSTR + q * 8];
            #pragma unroll
            for (int mt = 0; mt < 2; ++mt) {
                acc[g][mt][0] = __builtin_amdgcn_mfma_f32_16x16x32_bf16(afr[mt], bf0, acc[g][mt][0], 0, 0, 0);
                acc[g][mt][1] = __builtin_amdgcn_mfma_f32_16x16x32_bf16(afr[mt], bf1, acc[g][mt][1], 0, 0, 0);
            }
        }
        __syncthreads();
    }

    const float* bih = b_ih + u * (3 * H_);
    const float* bhh = b_hh + u * (3 * H_);
    if (g2 == 1) {
        #pragma unroll
        for (int nt = 0; nt < 2; ++nt) {
            const int col = wn * 32 + nt * 16 + lr;
            const float bhr = bhh[h0 + col], bhz = bhh[H_ + h0 + col], bhn = bhh[2 * H_ + h0 + col];
            #pragma unroll
            for (int mt = 0; mt < 2; ++mt)
                #pragma unroll
                for (int r = 0; r < 4; ++r) {
                    const int row = wm * 32 + mt * 16 + q * 4 + r;
                    smem.ep[0][row * ESTR + col] = acc[0][mt][nt][r] + bhr;
                    smem.ep[1][row * ESTR + col] = acc[1][mt][nt][r] + bhz;
                    smem.ep[2][row * ESTR + col] = acc[2][mt][nt][r] + bhn;
                }
        }
    }
    __syncthreads();
    if (g2 == 0) {
        #pragma unroll
        for (int nt = 0; nt < 2; ++nt) {
            const int col = wn * 32 + nt * 16 + lr, hcol = h0 + col;
            const float bir = bih[hcol], biz = bih[H_ + hcol], bin_ = bih[2 * H_ + hcol];
            #pragma unroll
            for (int mt = 0; mt < 2; ++mt)
                #pragma unroll
                for (int r = 0; r < 4; ++r) {
                    const int row = wm * 32 + mt * 16 + q * 4 + r;
                    const size_t gidx = ((size_t)(b0 + row) * U_ + u) * H_ + hcol;
                    const float hprev = hidden[gidx];
                    const float hr = smem.ep[0][row * ESTR + col];
                    const float hz = smem.ep[1][row * ESTR + col];
                    const float hn = smem.ep[2][row * ESTR + col];
                    const float xr = acc[0][mt][nt][r] + bir;
                    const float xz = acc[1][mt][nt][r] + biz;
                    const float xn = acc[2][mt][nt][r] + bin_;
                    const float rg = 1.f / (1.f + __expf(-(xr + hr)));
                    const float zg = 1.f / (1.f + __expf(-(xz + hz)));
                    const float ng = tanhf(xn + rg * hn);
                    out[gidx] = (1.f - zg) * ng + zg * hprev;
                }
        }
    }
}

extern "C" void kernel_launch(void* const* d_in, const int* in_sizes, int n_in,
                              void* d_out, int out_size, void* d_ws, size_t ws_size,
                              hipStream_t stream) {
    const float* inputs = (const float*)d_in[0];
    const float* hidden = (const float*)d_in[1];
    const float* W_ih   = (const float*)d_in[2];
    const float* W_hh   = (const float*)d_in[3];
    const float* b_ih   = (const float*)d_in[4];
    const float* b_hh   = (const float*)d_in[5];
    float* out = (float*)d_out;

    if (ws_size >= WS_NEED) {
        unsigned short* ws = (unsigned short*)d_ws;
        convert_bf16_kernel<<<NTOT / 2048, 256, 0, stream>>>(inputs, hidden, W_ih, W_hh, ws);
        dim3 grid(64, 8, 1);   // x = u*8+nb (x%8 = nb), y = mb (BM=128)
        gru_main_kernel<<<grid, 512, 0, stream>>>(ws, hidden, b_ih, b_hh, out);
    } else {
        dim3 grid(8, 16, 8);
        gru_fallback_kernel<<<grid, 512, 0, stream>>>(inputs, hidden, W_ih, W_hh, b_ih, b_hh, out);
    }
}